// Round 6
// baseline (312.640 us; speedup 1.0000x reference)
//
#include <hip/hip_runtime.h>

typedef unsigned short u16;
typedef unsigned int u32;
typedef __attribute__((ext_vector_type(8))) short bf16x8;   // 8 bf16 = 4 VGPRs
typedef __attribute__((ext_vector_type(4))) float f32x4;

// ---- ws layout (planar path) ----
// xp bf16 CHANNEL-PLANED [8 img][16 kc][66*66 rows][32 ch] : 35,684,352 B at 0
//   (plane stride 139,392 u16; img stride 2,230,272 u16)
// yb: 8 u16 lead pad + 2048 chunks x 16776 u16 + 16 u16 trail = 68,714,544 B
//   per (img,o) chunk: plane0 (65x66) @0 sz4296 | plane1 (65x64) @4296 sz4160
//                      plane2 (64x66) @8456 sz4224 | plane3 (64x64) @12680 sz4096
// Hy bf16 [9 pl][16 kc][256 o][32 ch] = 2,359,296 B (tap-plane stride 131,072 u16)
#define XP_BYTES 35684352
#define YB_BYTES 68714544
#define HY_OFF   (XP_BYTES + YB_BYTES)          // 104,398,896
#define WS_NEED  ((size_t)HY_OFF + 2359296)     // 106,758,192
#define CS 16776                                 // chunk stride (u16)

__device__ inline u16 f2bf(float f) {
  union { float f; unsigned u; } v; v.f = f;
  unsigned r = v.u + 0x7fffu + ((v.u >> 16) & 1u);
  return (u16)(r >> 16);
}

__device__ inline void gl_lds16(const u16* g, u16* l) {
  __builtin_amdgcn_global_load_lds(
      (const __attribute__((address_space(1))) unsigned int*)g,
      (__attribute__((address_space(3))) unsigned int*)l, 16, 0, 0);
}

// ---------------- x prep: f32 NCHW -> bf16 channel-planed with 1-px zero halo ----------
__global__ void xprep(const float* __restrict__ x, u16* __restrict__ xp) {
  __shared__ float tile[64 * 65];
  int bid = blockIdx.x;
  int cc = bid & 7, h = (bid >> 3) & 63, n = bid >> 9;
  int c0 = cc * 64;
  int t = threadIdx.x;
  const float* xb = x + ((size_t)(n * 512 + c0) * 64 + h) * 64;
  for (int r = 0; r < 16; ++r) {
    int flat = r * 256 + t;
    int ci = flat >> 6, w = flat & 63;
    tile[w * 65 + ci] = xb[(size_t)ci * 4096 + w];
  }
  __syncthreads();
  for (int r = 0; r < 8; ++r) {
    int flat = r * 256 + t;
    int pr = flat & 31;
    int w = flat >> 5;
    int ci = pr * 2;
    float v0 = tile[w * 65 + ci], v1 = tile[w * 65 + ci + 1];
    unsigned pk = (unsigned)f2bf(v0) | ((unsigned)f2bf(v1) << 16);
    int kcabs = cc * 2 + (ci >> 5);
    int chl = ci & 31;
    u16* dst = xp + (size_t)(n * 16 + kcabs) * 139392 +
               (size_t)((h + 1) * 66 + (w + 1)) * 32 + chl;
    *(unsigned*)dst = pk;
  }
  if (t < 64) {
    int seg = t >> 4;
    int colsel = (seg >> 1) ? 65 : 0;
    int pl = cc * 2 + (seg & 1);
    int ui = t & 15;
    u16* dst = xp + (size_t)(n * 16 + pl) * 139392 +
               (size_t)((h + 1) * 66 + colsel) * 32 + ui * 2;
    *(u32*)dst = 0u;
  }
  if (h == 0 || h == 63) {
    int rowbase = (h == 0) ? 0 : 65 * 66;
    for (int j = t; j < 2112; j += 256) {
      int seg = j >> 4;
      int ui = j & 15;
      int pl = cc * 2 + (seg & 1);
      int pos = seg >> 1;
      u16* dst = xp + (size_t)(n * 16 + pl) * 139392 +
                 (size_t)(rowbase + pos) * 32 + ui * 2;
      *(u32*)dst = 0u;
    }
  }
}

// ---------------- weight prep: modulate+demod, 9 tap planes, channel-planed ----------------
__global__ void wprep9(const float* __restrict__ w, u16* __restrict__ Hy) {
  __shared__ float wl[4608];
  __shared__ float red[256];
  int o = blockIdx.x, t = threadIdx.x;
  const float* wo = w + (size_t)o * 4608;
  float s = 0.f;
  for (int j = t; j < 4608; j += 256) { float v = wo[j]; wl[j] = v; s += v * v; }
  red[t] = s;
  __syncthreads();
  for (int st = 128; st; st >>= 1) { if (t < st) red[t] += red[t + st]; __syncthreads(); }
  float demod = rsqrtf(red[0] * (1.0f / 4608.0f) + 1e-6f);
  float scale = demod * 0.014731391274719739f;
  const int DY[9] = {0, 2, 0, 2, 0, 2, 1, 1, 1};
  const int DX[9] = {0, 0, 2, 2, 1, 1, 0, 2, 1};
  for (int i = t; i < 512; i += 256) {
    int kc = i >> 5, il = i & 31;
#pragma unroll
    for (int pl = 0; pl < 9; ++pl) {
      float g = wl[i * 9 + DY[pl] * 3 + DX[pl]] * scale;
      Hy[(size_t)(pl * 16 + kc) * 8192 + (size_t)o * 32 + il] = f2bf(g);
    }
  }
}

// ---------------- pass 1: conv-transpose y — BM256 x BN128, BK=32, FAT WAVES (R6) ----------
// 256 thr / 4 waves (2M x 2N); per-wave out 128m x 64o (acc[8][4]); 2 K-tiles/iter, 6 phases.
// R6 change (LDS-BW theory): per-K-tile ds_read_b128 count drops 80 -> 48 per block
// (Σ waves (M+N) frags: 8x(8+2) -> 4x(8+4)) for the same 128 MFMA. LDS reads/CU
// 12.2 -> 7.3 MB (~28 µs @85B/cyc) vs MFMA 39 µs -> MFMA-majority.
// LDS 48KiB: buf c at c*12288 u16: A [0,8192) u16 = 128 phys rows x 128 B
//   (logical i 0..255: p=i&127, hi=i>>7(=wm), slot=(hi*4+kc)^(p&7), byte=p*128+slot*16),
//   B [8192,12288) u16 = 64 phys rows x 128 B (o 0..127: p=o&63, hi=o>>6(=wn)).
// Staging: A = 4 issues x 4KB, B = 2 issues x 4KB; per wave-op dest linear
//   (thread t -> issue byte t*16); source pre-swizzled with the same bijection:
//   p = j*32+(t>>3), e = (t&7)^(p&7), i = (e>>2)*HALF + p, kc = e&3 (rule #21).
// Phases (tiles t0=2it in buf0, t0+1 in buf1):
//  p1 rd A0-3,B0-1 b0 | st A-iss01(t+1)->b1 | mfma [0..3]x[0..1] (8)
//  p2 rd B2-3 b0      | st A-iss23(t+1)->b1 | mfma [0..3]x[2..3] (8)
//  p3 rd A4-7 b0      | st B(t+2)->b0       | mfma [4..7]x[0..3] (16); WAITV2 [V0 last]
//  p4-p6 mirror on b1; st A(t+2)->b0 (p4,p5), B(t+3)->b1 (p6); WAITV2 at p6
// vmcnt ledger (ops/wave): prologue B(t0)2+A(t0)4+B(t1)2=8 -> WAITV2 leaves B(t1).
//  p3: 2(B t1)+4(A t1)+2(B t2)=8 in flight -> WAITV2 retires B(t1)+A(t1) (needed p4),
//  leaves B(t2). p6 symmetric. Last iter: WAITV0 at p3; p4-6 stage nothing (tile>=NK).
// WAR: A rows 0..63 staged p1 last read prior p4 (2+ barriers); rows 64..127 staged p2
//  last read prior p6 (1+ barrier); B staged p3 last read p1/p2 (1-2 barriers). All
//  reads complete at their phase's WAITL before the closing barrier preceding the stage.
#define BARR() __builtin_amdgcn_s_barrier()
#define WAITL() do { asm volatile("s_waitcnt lgkmcnt(0)" ::: "memory"); __builtin_amdgcn_sched_barrier(0); } while (0)
#define WAITV2() do { asm volatile("s_waitcnt vmcnt(2)" ::: "memory"); __builtin_amdgcn_sched_barrier(0); } while (0)
#define WAITV0() do { asm volatile("s_waitcnt vmcnt(0)" ::: "memory"); __builtin_amdgcn_sched_barrier(0); } while (0)

__device__ __forceinline__ void rdA4(const u16* sb, int tib, int la, int grp, int wm,
                                     bf16x8 af[4]) {
#pragma unroll
  for (int ti = 0; ti < 4; ++ti) {
    int p = (tib + ti) * 16 + la;
    int slot = (wm * 4 + grp) ^ (p & 7);
    af[ti] = *(const bf16x8*)(sb + p * 64 + slot * 8);
  }
}

__device__ __forceinline__ void rdB2(const u16* sb, int njb, int la, int grp, int wn,
                                     bf16x8 bf[2]) {
#pragma unroll
  for (int nj = 0; nj < 2; ++nj) {
    int p = (njb + nj) * 16 + la;
    int slot = (wn * 4 + grp) ^ (p & 7);
    bf[nj] = *(const bf16x8*)(sb + 8192 + p * 64 + slot * 8);
  }
}

template <int MIB, int NJ0>
__device__ __forceinline__ void qm8(const bf16x8 af[4], const bf16x8 bf[2],
                                    f32x4 acc[8][4]) {
#pragma unroll
  for (int ti = 0; ti < 4; ++ti)
#pragma unroll
    for (int nj = 0; nj < 2; ++nj)
      acc[MIB + ti][NJ0 + nj] = __builtin_amdgcn_mfma_f32_16x16x32_bf16(
          af[ti], bf[nj], acc[MIB + ti][NJ0 + nj], 0, 0, 0);
}

__device__ __forceinline__ void stA1(const u16* __restrict__ xp, u16* d,
                                     int tile, int NK, u32 a,
                                     u32 adj1, u32 adj2, u32 adj3) {
  if (tile < NK) {
    int tap = tile >> 4;
    u32 ko = (u32)((tile & 15) * 139392);   // kc plane stride (u16)
    u32 adj = tap == 0 ? 0u : (tap == 1 ? adj1 : (tap == 2 ? adj2 : adj3));
    gl_lds16(xp + (a + ko - adj), d);
  }
}

__device__ __forceinline__ void stB1(const u16* __restrict__ hb, u16* d,
                                     int tile, int NK, u32 b) {
  if (tile < NK) {
    int tap = tile >> 4;
    u32 ko = (u32)(tap * 131072 + (tile & 15) * 8192);
    gl_lds16(hb + (b + ko), d);
  }
}

__global__ __launch_bounds__(256, 2) void conv_y(const u16* __restrict__ xp,
                                                 const u16* __restrict__ Hy,
                                                 u16* __restrict__ yb) {
  __shared__ __align__(16) u16 su[24576];   // 48 KiB: 2 x (A 8192 u16 + B 4096 u16)

  int bid = blockIdx.x;
  int t = threadIdx.x;
  int wid = t >> 6, lane = t & 63;

  // img -> XCD pinned (8 imgs, 8 XCDs); heavy classes first within each img
  int img = bid & 7;
  int kk = bid >> 3;                       // 0..133
  int mt, oh, Wp, CNT, NTAP, PB, PO, STLIM;
  u32 adj1 = 0, adj2 = 0, adj3 = 0;        // (du*66+dv)*32 u16 per tap (tap0 always 0)
  if (kk < 34)       { int k2 = kk;       mt = k2 >> 1; oh = k2 & 1; Wp = 66; CNT = 4290; NTAP = 4; PB = 0; PO = 0;     STLIM = 4296;
                       adj1 = 2112u; adj2 = 32u; adj3 = 2144u; }
  else if (kk < 68)  { int k2 = kk - 34;  mt = k2 >> 1; oh = k2 & 1; Wp = 64; CNT = 4160; NTAP = 2; PB = 4; PO = 4296;  STLIM = 4160;
                       adj1 = 2112u; }
  else if (kk < 102) { int k2 = kk - 68;  mt = k2 >> 1; oh = k2 & 1; Wp = 66; CNT = 4224; NTAP = 2; PB = 6; PO = 8456;  STLIM = 4224;
                       adj1 = 32u; }
  else               { int k2 = kk - 102; mt = k2 >> 1; oh = k2 & 1; Wp = 64; CNT = 4096; NTAP = 1; PB = 8; PO = 12680; STLIM = 4096; }

  int m0 = mt * 256;
  int o0 = oh * 128;
  int NK = NTAP * 16;                       // K-tiles of 32 ch
  int NITER = NTAP * 8;
  const u16* hb = Hy + (size_t)PB * 131072;

  int wm = wid >> 1, wn = wid & 1;          // 2M x 2N waves: wave = 128m x 64o
  int la = lane & 15, grp = lane >> 4;

  // staging source addrs (pre-swizzled, per issue)
  int tp = t >> 3, ts = t & 7;
  u32 gA[4], gBv[2];
  {
    u32 ib = (u32)img * 2230272u;           // img plane-base (u16)
#pragma unroll
    for (int j = 0; j < 4; ++j) {
      int p = j * 32 + tp;
      int e = ts ^ (p & 7);
      int ii = (e >> 2) * 128 + p;          // logical m-index 0..255
      int kc = e & 3;
      int m = m0 + ii;
      if (m > CNT - 1) m = CNT - 1;         // clamp (garbage compute, store-guarded)
      u32 a = (u32)m / (u32)Wp;
      u32 b = (u32)m - a * (u32)Wp;
      gA[j] = ib + ((a + 1) * 66 + (b + 1)) * 32 + kc * 8;
    }
#pragma unroll
    for (int j = 0; j < 2; ++j) {
      int p = j * 32 + tp;
      int e = ts ^ (p & 7);
      int ol = (e >> 2) * 64 + p;           // logical o-index 0..127
      int kc = e & 3;
      gBv[j] = (u32)((o0 + ol) * 32 + kc * 8);
    }
  }
  int ws = wid * 512;                       // per-wave staging slice (1 KiB)

  f32x4 acc[8][4];
#pragma unroll
  for (int i = 0; i < 8; ++i)
#pragma unroll
    for (int j = 0; j < 4; ++j) acc[i][j] = (f32x4){0.f, 0.f, 0.f, 0.f};

  // ---- prologue: B(t0) 2, A(t0) 4, B(t1) 2; WAITV2 leaves B(t1) in flight
  stB1(hb, su + 8192 + ws, 0, NK, gBv[0]);
  stB1(hb, su + 10240 + ws, 0, NK, gBv[1]);
  stA1(xp, su + 0 + ws, 0, NK, gA[0], adj1, adj2, adj3);
  stA1(xp, su + 2048 + ws, 0, NK, gA[1], adj1, adj2, adj3);
  stA1(xp, su + 4096 + ws, 0, NK, gA[2], adj1, adj2, adj3);
  stA1(xp, su + 6144 + ws, 0, NK, gA[3], adj1, adj2, adj3);
  stB1(hb, su + 20480 + ws, 1, NK, gBv[0]);
  stB1(hb, su + 22528 + ws, 1, NK, gBv[1]);
  WAITV2();
  BARR();

  bf16x8 afA[4], afB[4], bfA[2], bfB[2];

#pragma unroll 1
  for (int it = 0; it < NITER; ++it) {
    int t0 = 2 * it;
    bool more = (it + 1 < NITER);

    // ---- p1: buf0 | rd A0-3, B0-1 | st A-iss01(t0+1)->buf1 | mfma [0..3]x[0..1]
    rdA4(su, 0, la, grp, wm, afA);
    rdB2(su, 0, la, grp, wn, bfA);
    stA1(xp, su + 12288 + ws, t0 + 1, NK, gA[0], adj1, adj2, adj3);
    stA1(xp, su + 14336 + ws, t0 + 1, NK, gA[1], adj1, adj2, adj3);
    BARR(); WAITL();
    __builtin_amdgcn_s_setprio(1); qm8<0, 0>(afA, bfA, acc); __builtin_amdgcn_s_setprio(0);
    BARR();
    // ---- p2: rd B2-3 | st A-iss23(t0+1)->buf1 | mfma [0..3]x[2..3]
    rdB2(su, 2, la, grp, wn, bfB);
    stA1(xp, su + 16384 + ws, t0 + 1, NK, gA[2], adj1, adj2, adj3);
    stA1(xp, su + 18432 + ws, t0 + 1, NK, gA[3], adj1, adj2, adj3);
    BARR(); WAITL();
    __builtin_amdgcn_s_setprio(1); qm8<0, 2>(afA, bfB, acc); __builtin_amdgcn_s_setprio(0);
    BARR();
    // ---- p3: rd A4-7 | st B(t0+2)->buf0 | mfma [4..7]x[0..3] | counted vmcnt
    rdA4(su, 4, la, grp, wm, afB);
    stB1(hb, su + 8192 + ws, t0 + 2, NK, gBv[0]);
    stB1(hb, su + 10240 + ws, t0 + 2, NK, gBv[1]);
    BARR(); WAITL();
    __builtin_amdgcn_s_setprio(1);
    qm8<4, 0>(afB, bfA, acc); qm8<4, 2>(afB, bfB, acc);
    __builtin_amdgcn_s_setprio(0);
    if (more) { WAITV2(); } else { WAITV0(); }
    BARR();
    // ---- p4: buf1 | rd A0-3, B0-1 | st A-iss01(t0+2)->buf0
    rdA4(su + 12288, 0, la, grp, wm, afA);
    rdB2(su + 12288, 0, la, grp, wn, bfA);
    stA1(xp, su + 0 + ws, t0 + 2, NK, gA[0], adj1, adj2, adj3);
    stA1(xp, su + 2048 + ws, t0 + 2, NK, gA[1], adj1, adj2, adj3);
    BARR(); WAITL();
    __builtin_amdgcn_s_setprio(1); qm8<0, 0>(afA, bfA, acc); __builtin_amdgcn_s_setprio(0);
    BARR();
    // ---- p5: rd B2-3 | st A-iss23(t0+2)->buf0
    rdB2(su + 12288, 2, la, grp, wn, bfB);
    stA1(xp, su + 4096 + ws, t0 + 2, NK, gA[2], adj1, adj2, adj3);
    stA1(xp, su + 6144 + ws, t0 + 2, NK, gA[3], adj1, adj2, adj3);
    BARR(); WAITL();
    __builtin_amdgcn_s_setprio(1); qm8<0, 2>(afA, bfB, acc); __builtin_amdgcn_s_setprio(0);
    BARR();
    // ---- p6: rd A4-7 | st B(t0+3)->buf1 | counted vmcnt
    rdA4(su + 12288, 4, la, grp, wm, afB);
    stB1(hb, su + 20480 + ws, t0 + 3, NK, gBv[0]);
    stB1(hb, su + 22528 + ws, t0 + 3, NK, gBv[1]);
    BARR(); WAITL();
    __builtin_amdgcn_s_setprio(1);
    qm8<4, 0>(afB, bfA, acc); qm8<4, 2>(afB, bfB, acc);
    __builtin_amdgcn_s_setprio(0);
    if (more) { WAITV2(); }
    BARR();
  }

  // ---- epilogue: two o-half rounds through LDS [64 o][256 m] u16 (32 KiB), XOR chunks
  WAITV0();          // defensive drain (ledger says already 0 here)
  __syncthreads();
  u16* ybp = yb + 8;
#pragma unroll 1
  for (int r = 0; r < 2; ++r) {
    if (wn == r) {
#pragma unroll
      for (int nj = 0; nj < 4; ++nj) {
        int orl = nj * 16 + la;
        int x7 = orl & 7;
#pragma unroll
        for (int mi = 0; mi < 8; ++mi)
#pragma unroll
          for (int jp = 0; jp < 2; ++jp) {
            int ml = wm * 128 + mi * 16 + grp * 4 + jp * 2;
            u32 pk = (u32)f2bf(acc[mi][nj][jp * 2]) |
                     ((u32)f2bf(acc[mi][nj][jp * 2 + 1]) << 16);
            *(u32*)(su + orl * 256 + (((ml >> 3) ^ x7) * 8) + (ml & 7)) = pk;
          }
      }
    }
    __syncthreads();
    {
      int ol = t >> 2, s2 = t & 3;
      int og = o0 + r * 64 + ol;
      size_t gb = (size_t)(img * 256 + og) * CS + PO + m0;
      int x7 = ol & 7;
#pragma unroll
      for (int i = 0; i < 8; ++i) {
        int cidx = s2 * 8 + i;
        int m = cidx * 8;
        if (m0 + m < STLIM)
          *(bf16x8*)(ybp + gb + m) = *(const bf16x8*)(su + ol * 256 + ((cidx ^ x7) * 8));
      }
    }
    if (r == 0) __syncthreads();
  }
}

// ---------------- pass 2: depthwise FIR on planar y; thread = 4p x 8q z block ----------------
// z[p][q] = (1/16) sum f1[s]f1[t] y[p+s-1][q+t-1], f1={1,3,3,1}.
__global__ void fir2(const u16* __restrict__ yb, float* __restrict__ z) {
  int flat = blockIdx.x * 256 + threadIdx.x;
  int qh = flat & 15, phb = (flat >> 4) & 31, o = (flat >> 9) & 255, n = flat >> 17;
  const u16* cb = yb + 8 + (size_t)(n * 256 + o) * CS;
  int a0 = 2 * phb - 1;
  int b0 = 4 * qh - 1;

  float out[4][8];
#pragma unroll
  for (int i = 0; i < 4; ++i)
#pragma unroll
    for (int j = 0; j < 8; ++j) out[i][j] = 0.f;

  const int PO_[4] = {0, 4296, 8456, 12680};
  const int WP_[4] = {66, 64, 66, 64};
  const int HA_[4] = {65, 65, 64, 64};
  const int WB_[4] = {65, 64, 65, 64};

#pragma unroll
  for (int ph = 0; ph < 4; ++ph) {
    int rp = ph >> 1, rq = ph & 1;
    const u16* pb = cb + PO_[ph];
    float hcol[4][8];
#pragma unroll
    for (int la = 0; la < 4; ++la) {
      if (rp == 0 && la == 0) continue;
      int ag = a0 + la;
      bool rv = (ag >= 0) && (ag < HA_[ph]);
      const u16* rb = pb + (ag * WP_[ph] + b0 - 1);
      u32 ls[4];
      ls[0] = *(const u32*)(rb);
      ls[1] = *(const u32*)(rb + 2);
      ls[2] = *(const u32*)(rb + 4);
      ls[3] = *(const u32*)(rb + 6);
      float v[6];
#pragma unroll
      for (int lb = 0; lb < 6; ++lb) {
        int jj = lb + 1;
        u32 w16 = (jj & 1) ? (ls[jj >> 1] >> 16) : (ls[jj >> 1] & 0xffffu);
        float fv = __uint_as_float(w16 << 16);
        int bg = b0 + lb;
        bool ok = rv && (bg >= 0) && (bg < WB_[ph]);
        v[lb] = ok ? fv : 0.f;
      }
#pragma unroll
      for (int e = 0; e < 4; ++e) {
        if (rq == 0) {
          hcol[la][2 * e]     = 3.f * v[e + 1] + v[e + 2];
          hcol[la][2 * e + 1] = v[e + 1] + 3.f * v[e + 2];
        } else {
          hcol[la][2 * e]     = v[e] + 3.f * v[e + 1];
          hcol[la][2 * e + 1] = 3.f * v[e + 1] + v[e + 2];
        }
      }
    }
#pragma unroll
    for (int jq = 0; jq < 8; ++jq) {
      if (rp == 0) {
        out[0][jq] += 3.f * hcol[1][jq] + hcol[2][jq];
        out[1][jq] += hcol[1][jq] + 3.f * hcol[2][jq];
        out[2][jq] += 3.f * hcol[2][jq] + hcol[3][jq];
        out[3][jq] += hcol[2][jq] + 3.f * hcol[3][jq];
      } else {
        out[0][jq] += hcol[0][jq] + 3.f * hcol[1][jq];
        out[1][jq] += 3.f * hcol[1][jq] + hcol[2][jq];
        out[2][jq] += hcol[1][jq] + 3.f * hcol[2][jq];
        out[3][jq] += 3.f * hcol[2][jq] + hcol[3][jq];
      }
    }
  }

  float* zb = z + ((size_t)(n * 256 + o) * 128 + phb * 4) * 128 + qh * 8;
#pragma unroll
  for (int ip = 0; ip < 4; ++ip) {
    f32x4 v0, v1;
#pragma unroll
    for (int j = 0; j < 4; ++j) { v0[j] = out[ip][j] * 0.0625f; v1[j] = out[ip][j + 4] * 0.0625f; }
    *(f32x4*)(zb + (size_t)ip * 128) = v0;
    *(f32x4*)(zb + (size_t)ip * 128 + 4) = v1;
  }
}

// ================= fallback path (R2, proven): FIR-folded fused conv =================
__global__ void xprep_flat(const float* __restrict__ x, u16* __restrict__ xp) {
  __shared__ float tile[64 * 65];
  int bid = blockIdx.x;
  int cc = bid & 7, h = (bid >> 3) & 63, n = bid >> 9;
  int c0 = cc * 64;
  int t = threadIdx.x;
  const float* xb = x + ((size_t)(n * 512 + c0) * 64 + h) * 64;
  for (int r = 0; r < 16; ++r) {
    int flat = r * 256 + t;
    int ci = flat >> 6, w = flat & 63;
    tile[w * 65 + ci] = xb[(size_t)ci * 4096 + w];
  }
  __syncthreads();
  u16* xpb = xp + ((size_t)(n * 66 + h + 1) * 66 + 1) * 512 + c0;
  for (int r = 0; r < 8; ++r) {
    int flat = r * 256 + t;
    int pr = flat & 31;
    int w = flat >> 5;
    int ci = pr * 2;
    float v0 = tile[w * 65 + ci], v1 = tile[w * 65 + ci + 1];
    unsigned pk = (unsigned)f2bf(v0) | ((unsigned)f2bf(v1) << 16);
    *(unsigned*)(xpb + (size_t)w * 512 + ci) = pk;
  }
  u16* rowbase = xp + ((size_t)(n * 66 + h + 1) * 66) * 512 + c0;
  if (t < 32) *(u32*)(rowbase + 2 * t) = 0u;
  else if (t < 64) *(u32*)(rowbase + (size_t)65 * 512 + 2 * (t - 32)) = 0u;
  if (h == 0) {
    u16* r0 = xp + ((size_t)(n * 66) * 66) * 512 + c0;
    for (int j = t; j < 2112; j += 256) {
      int col = j >> 5, wi = j & 31;
      *(u32*)(r0 + (size_t)col * 512 + 2 * wi) = 0u;
    }
  }
  if (h == 63) {
    u16* r65 = xp + ((size_t)(n * 66 + 65) * 66) * 512 + c0;
    for (int j = t; j < 2112; j += 256) {
      int col = j >> 5, wi = j & 31;
      *(u32*)(r65 + (size_t)col * 512 + 2 * wi) = 0u;
    }
  }
}

__global__ void wprep36(const float* __restrict__ w, u16* __restrict__ Hm) {
  __shared__ float wl[4608];
  __shared__ float red[256];
  int o = blockIdx.x, t = threadIdx.x;
  const float* wo = w + (size_t)o * 4608;
  float s = 0.f;
  for (int j = t; j < 4608; j += 256) { float v = wo[j]; wl[j] = v; s += v * v; }
  red[t] = s;
  __syncthreads();
  for (int st = 128; st; st >>= 1) { if (t < st) red[t] += red[t + st]; __syncthreads(); }
  float demod = rsqrtf(red[0] * (1.0f / 4608.0f) + 1e-6f);
  float scale = demod * 0.014731391274719739f;
  const float F1[4] = {1.f, 3.f, 3.f, 1.f};
  for (int i = t; i < 512; i += 256) {
    float wm[9];
    for (int k = 0; k < 9; ++k) wm[k] = wl[i * 9 + k] * scale;
    for (int rp = 0; rp < 2; ++rp)
      for (int rq = 0; rq < 2; ++rq)
        for (int u = 0; u < 3; ++u)
          for (int v = 0; v < 3; ++v) {
            int s_ = 2 - 2 * u + rp, t_ = 2 - 2 * v + rq;
            float g = 0.f;
            for (int dy = 0; dy < 3; ++dy) {
              int a = dy + 1 - s_;
              if (a < 0 || a > 3) continue;
              for (int dx = 0; dx < 3; ++dx) {
                int b = dx + 1 - t_;
                if (b < 0 || b > 3) continue;
                g += wm[dy * 3 + dx] * (F1[a] * F1[b]);
              }
            }
            g *= 0.0625f;
            Hm[(size_t)((rp * 2 + rq) * 9 + u * 3 + v) * 131072 + (size_t)o * 512 + i] = f2bf(g);
          }
  }
}

__global__ __launch_bounds__(256) void conv_main(const u16* __restrict__ xp,
                                                 const u16* __restrict__ Hm,
                                                 float* __restrict__ z) {
  __shared__ __align__(16) float smemf[8448];
  u16* su = (u16*)smemf;
  int bid = blockIdx.x;
  int sub = bid & 7;
  int rp = sub >> 2;
  int o0 = (sub & 3) * 64;
  int mtile = bid >> 3;
  int n_img = mtile >> 5;
  int hp0 = (mtile & 31) * 2;
  int t = threadIdx.x;
  int wave = t >> 6, lane = t & 63;
  int wm0 = (wave & 1) * 64;
  int wn0 = (wave >> 1) * 32;
  int la = lane & 15;
  int ks = (lane >> 4) * 8;
  int rsel = t >> 2;
  int koff = (t & 3) * 8;
  f32x4 acc[2][4][2];
#pragma unroll
  for (int a = 0; a < 2; ++a)
#pragma unroll
    for (int b = 0; b < 4; ++b)
#pragma unroll
      for (int c = 0; c < 2; ++c)
        acc[a][b][c] = (f32x4){0.f, 0.f, 0.f, 0.f};
#pragma unroll 1
  for (int tap = 0; tap < 9; ++tap) {
    int du = tap / 3, dv = tap - du * 3;
    const u16* gA0 = xp + ((size_t)(n_img * 66 + hp0 + du) * 66 + dv) * 512;
    const u16* gB0 = Hm + (size_t)(rp * 18 + tap) * 131072 + (size_t)(o0 + rsel) * 512 + koff;
    const u16* gAr0 = gA0 + (size_t)rsel * 512 + koff;
    const u16* gAr1 = gA0 + (size_t)(66 + rsel) * 512 + koff;
#pragma unroll 1
    for (int kc = 0; kc < 16; ++kc) {
      int c0 = kc * 32;
      __syncthreads();
      gl_lds16(gAr0 + c0, su + wave * 512);
      gl_lds16(gAr1 + c0, su + 2048 + wave * 512);
      gl_lds16(gB0 + c0,              su + 4096 + wave * 512);
      gl_lds16(gB0 + 9 * 131072 + c0, su + 6144 + wave * 512);
      __syncthreads();
      bf16x8 af[4];
#pragma unroll
      for (int ti = 0; ti < 4; ++ti)
        af[ti] = *(const bf16x8*)(su + (wm0 + ti * 16 + la) * 32 + ks);
      bf16x8 bfr[2][2];
#pragma unroll
      for (int rqq = 0; rqq < 2; ++rqq)
#pragma unroll
        for (int tj = 0; tj < 2; ++tj)
          bfr[rqq][tj] = *(const bf16x8*)(su + 4096 + rqq * 2048 + (wn0 + tj * 16 + la) * 32 + ks);
#pragma unroll
      for (int rqq = 0; rqq < 2; ++rqq)
#pragma unroll
        for (int ti = 0; ti < 4; ++ti)
#pragma unroll
          for (int tj = 0; tj < 2; ++tj)
            acc[rqq][ti][tj] = __builtin_amdgcn_mfma_f32_16x16x32_bf16(
                af[ti], bfr[rqq][tj], acc[rqq][ti][tj], 0, 0, 0);
    }
  }
  __syncthreads();
  float* lws = smemf + wave * 2112;
  int p = 2 * (hp0 + (wave & 1)) + rp;
#pragma unroll
  for (int tj = 0; tj < 2; ++tj) {
#pragma unroll
    for (int rqq = 0; rqq < 2; ++rqq)
#pragma unroll
      for (int ti = 0; ti < 4; ++ti) {
        int wqb = ti * 16 + (lane >> 4) * 4;
        f32x4 v = acc[rqq][ti][tj];
#pragma unroll
        for (int r = 0; r < 4; ++r)
          lws[la * 132 + 2 * (wqb + r) + rqq] = v[r];
      }
    __syncthreads();
    int obase = o0 + wn0 + tj * 16;
#pragma unroll
    for (int c = 0; c < 8; ++c) {
      int idx = c * 64 + lane;
      int ol = idx >> 5, q4 = (idx & 31) * 4;
      f32x4 vv = *(const f32x4*)(lws + ol * 132 + q4);
      *(f32x4*)(z + (((size_t)n_img * 256 + obase + ol) * 128 + p) * 128 + q4) = vv;
    }
    __syncthreads();
  }
}

extern "C" void kernel_launch(void* const* d_in, const int* in_sizes, int n_in,
                              void* d_out, int out_size, void* d_ws, size_t ws_size,
                              hipStream_t stream) {
  const float* x = (const float*)d_in[0];
  const float* w = (const float*)d_in[1];
  float* z = (float*)d_out;
  u16* xp = (u16*)d_ws;

  if (ws_size >= WS_NEED) {
    u16* yb = (u16*)((char*)d_ws + XP_BYTES);
    u16* hy = (u16*)((char*)d_ws + HY_OFF);
    xprep<<<4096, 256, 0, stream>>>(x, xp);       // channel-planed; self-zeroing halos
    wprep9<<<256, 256, 0, stream>>>(w, hy);
    conv_y<<<1072, 256, 0, stream>>>(xp, hy, yb); // 8 img x 134 tiles, XCD-pinned, 4-wave
    fir2<<<4096, 256, 0, stream>>>(yb, z);
  } else {
    u16* Hm = (u16*)((char*)d_ws + XP_BYTES);
    hipMemsetAsync(xp, 0, XP_BYTES, stream);
    xprep_flat<<<4096, 256, 0, stream>>>(x, xp);
    wprep36<<<256, 256, 0, stream>>>(w, Hm);
    conv_main<<<2048, 256, 0, stream>>>(xp, Hm, z);
  }
}

// Round 7
// 306.438 us; speedup vs baseline: 1.0202x; 1.0202x over previous
//
#include <hip/hip_runtime.h>

typedef unsigned short u16;
typedef unsigned int u32;
typedef __attribute__((ext_vector_type(8))) short bf16x8;   // 8 bf16 = 4 VGPRs
typedef __attribute__((ext_vector_type(4))) float f32x4;

// ---- ws layout (planar path) ----
// xp bf16 CHANNEL-PLANED [8 img][16 kc][66*66 rows][32 ch] : 35,684,352 B at 0
//   (plane stride 139,392 u16; img stride 2,230,272 u16)
// yb: 8 u16 lead pad + 2048 chunks x 16776 u16 + 16 u16 trail = 68,714,544 B
//   per (img,o) chunk: plane0 (65x66) @0 sz4296 | plane1 (65x64) @4296 sz4160
//                      plane2 (64x66) @8456 sz4224 | plane3 (64x64) @12680 sz4096
// Hy bf16 [9 pl][16 kc][256 o][32 ch] = 2,359,296 B (tap-plane stride 131,072 u16)
#define XP_BYTES 35684352
#define YB_BYTES 68714544
#define HY_OFF   (XP_BYTES + YB_BYTES)          // 104,398,896
#define WS_NEED  ((size_t)HY_OFF + 2359296)     // 106,758,192
#define CS 16776                                 // chunk stride (u16)

__device__ inline u16 f2bf(float f) {
  union { float f; unsigned u; } v; v.f = f;
  unsigned r = v.u + 0x7fffu + ((v.u >> 16) & 1u);
  return (u16)(r >> 16);
}

__device__ inline void gl_lds16(const u16* g, u16* l) {
  __builtin_amdgcn_global_load_lds(
      (const __attribute__((address_space(1))) unsigned int*)g,
      (__attribute__((address_space(3))) unsigned int*)l, 16, 0, 0);
}

// ---------------- x prep: f32 NCHW -> bf16 channel-planed with 1-px zero halo ----------
__global__ void xprep(const float* __restrict__ x, u16* __restrict__ xp) {
  __shared__ float tile[64 * 65];
  int bid = blockIdx.x;
  int cc = bid & 7, h = (bid >> 3) & 63, n = bid >> 9;
  int c0 = cc * 64;
  int t = threadIdx.x;
  const float* xb = x + ((size_t)(n * 512 + c0) * 64 + h) * 64;
  for (int r = 0; r < 16; ++r) {
    int flat = r * 256 + t;
    int ci = flat >> 6, w = flat & 63;
    tile[w * 65 + ci] = xb[(size_t)ci * 4096 + w];
  }
  __syncthreads();
  for (int r = 0; r < 8; ++r) {
    int flat = r * 256 + t;
    int pr = flat & 31;
    int w = flat >> 5;
    int ci = pr * 2;
    float v0 = tile[w * 65 + ci], v1 = tile[w * 65 + ci + 1];
    unsigned pk = (unsigned)f2bf(v0) | ((unsigned)f2bf(v1) << 16);
    int kcabs = cc * 2 + (ci >> 5);
    int chl = ci & 31;
    u16* dst = xp + (size_t)(n * 16 + kcabs) * 139392 +
               (size_t)((h + 1) * 66 + (w + 1)) * 32 + chl;
    *(unsigned*)dst = pk;
  }
  if (t < 64) {
    int seg = t >> 4;
    int colsel = (seg >> 1) ? 65 : 0;
    int pl = cc * 2 + (seg & 1);
    int ui = t & 15;
    u16* dst = xp + (size_t)(n * 16 + pl) * 139392 +
               (size_t)((h + 1) * 66 + colsel) * 32 + ui * 2;
    *(u32*)dst = 0u;
  }
  if (h == 0 || h == 63) {
    int rowbase = (h == 0) ? 0 : 65 * 66;
    for (int j = t; j < 2112; j += 256) {
      int seg = j >> 4;
      int ui = j & 15;
      int pl = cc * 2 + (seg & 1);
      int pos = seg >> 1;
      u16* dst = xp + (size_t)(n * 16 + pl) * 139392 +
                 (size_t)(rowbase + pos) * 32 + ui * 2;
      *(u32*)dst = 0u;
    }
  }
}

// ---------------- weight prep: modulate+demod, 9 tap planes, channel-planed ----------------
__global__ void wprep9(const float* __restrict__ w, u16* __restrict__ Hy) {
  __shared__ float wl[4608];
  __shared__ float red[256];
  int o = blockIdx.x, t = threadIdx.x;
  const float* wo = w + (size_t)o * 4608;
  float s = 0.f;
  for (int j = t; j < 4608; j += 256) { float v = wo[j]; wl[j] = v; s += v * v; }
  red[t] = s;
  __syncthreads();
  for (int st = 128; st; st >>= 1) { if (t < st) red[t] += red[t + st]; __syncthreads(); }
  float demod = rsqrtf(red[0] * (1.0f / 4608.0f) + 1e-6f);
  float scale = demod * 0.014731391274719739f;
  const int DY[9] = {0, 2, 0, 2, 0, 2, 1, 1, 1};
  const int DX[9] = {0, 0, 2, 2, 1, 1, 0, 2, 1};
  for (int i = t; i < 512; i += 256) {
    int kc = i >> 5, il = i & 31;
#pragma unroll
    for (int pl = 0; pl < 9; ++pl) {
      float g = wl[i * 9 + DY[pl] * 3 + DX[pl]] * scale;
      Hy[(size_t)(pl * 16 + kc) * 8192 + (size_t)o * 32 + il] = f2bf(g);
    }
  }
}

// ---------------- pass 1: conv-transpose y — FAT PHASE, 3-deep buffers (R7) ----------
// 256 thr / 4 waves (2M x 2N); per-wave out 128m x 64o (acc[8][4]); ONE phase per K-tile:
//   { rd 12 frags buf[t%3] | issue 6 DMA (tile t+2 -> buf[(t+2)%3]) | 32 MFMA } vmcnt; barrier.
// NO explicit lgkmcnt/sched_barrier pins: compiler emits fine-grained lgkmcnt between
// ds_read and dependent MFMA (m97-verified), so reads overlap the MFMA cluster.
// Barriers: 1 per K-tile (was 3). MFMA per barrier: 32 (was 10.7).
// LDS 72KiB = 3 bufs x 12288 u16 (A [0,8192): 128 phys rows x 128B; B [8192,12288):
//   64 rows x 128B). Slot math (R4-proven, ~550-815K conflicts):
//   A: logical i 0..255 -> p=i&127, hi=i>>7, slot=(hi*4+kc)^(p&7), byte=p*128+slot*16;
//   B: o 0..127 -> p=o&63, hi=o>>6. Stage dest linear (thread t -> byte t*16/issue);
//   source pre-swizzled with the same bijection (rule #21).
// Hazards (single barrier audit):
//  - reads buf[cur]: tile t landed (vmcnt ledger); staging never targets cur in phases
//    t-1 (->(t+1)%3) or t (->(t+2)%3). OK.
//  - DMA into buf[(t+2)%3]: its last reads (tile t-1, phase t-1) completed before the
//    t-1 closing barrier (compiler lgkmcnt before consuming MFMA => data in regs). OK.
//  - vmcnt ledger (FIFO/wave): prologue stages tile0(6)+tile1(6)=12 -> WAITV6 retires
//    tile0. Phase t: +6 (tile t+2) -> 12 in flight -> WAITV6 retires tile t+1 (needed
//    next phase), leaves tile t+2. Tail: t+2>=NK stages nothing -> WAITV0 drains
//    tile NK-1 at t=NK-2; epilogue starts drained.
//  - WAITV asm has "memory" clobber: next-phase ds_reads/stages can't hoist above it;
//    this phase's stage issues can't sink below it (ledger integrity).
#define BARR() __builtin_amdgcn_s_barrier()
#define WAITV6() do { asm volatile("s_waitcnt vmcnt(6)" ::: "memory"); __builtin_amdgcn_sched_barrier(0); } while (0)
#define WAITV0() do { asm volatile("s_waitcnt vmcnt(0)" ::: "memory"); __builtin_amdgcn_sched_barrier(0); } while (0)

__device__ __forceinline__ void rdA4(const u16* sb, int tib, int la, int grp, int wm,
                                     bf16x8 af[4]) {
#pragma unroll
  for (int ti = 0; ti < 4; ++ti) {
    int p = (tib + ti) * 16 + la;
    int slot = (wm * 4 + grp) ^ (p & 7);
    af[ti] = *(const bf16x8*)(sb + p * 64 + slot * 8);
  }
}

__device__ __forceinline__ void rdB2(const u16* sb, int njb, int la, int grp, int wn,
                                     bf16x8 bf[2]) {
#pragma unroll
  for (int nj = 0; nj < 2; ++nj) {
    int p = (njb + nj) * 16 + la;
    int slot = (wn * 4 + grp) ^ (p & 7);
    bf[nj] = *(const bf16x8*)(sb + 8192 + p * 64 + slot * 8);
  }
}

__device__ __forceinline__ void stA1(const u16* __restrict__ xp, u16* d,
                                     int tile, int NK, u32 a,
                                     u32 adj1, u32 adj2, u32 adj3) {
  if (tile < NK) {
    int tap = tile >> 4;
    u32 ko = (u32)((tile & 15) * 139392);   // kc plane stride (u16)
    u32 adj = tap == 0 ? 0u : (tap == 1 ? adj1 : (tap == 2 ? adj2 : adj3));
    gl_lds16(xp + (a + ko - adj), d);
  }
}

__device__ __forceinline__ void stB1(const u16* __restrict__ hb, u16* d,
                                     int tile, int NK, u32 b) {
  if (tile < NK) {
    int tap = tile >> 4;
    u32 ko = (u32)(tap * 131072 + (tile & 15) * 8192);
    gl_lds16(hb + (b + ko), d);
  }
}

__global__ __launch_bounds__(256, 2) void conv_y(const u16* __restrict__ xp,
                                                 const u16* __restrict__ Hy,
                                                 u16* __restrict__ yb) {
  __shared__ __align__(16) u16 su[36864];   // 72 KiB: 3 x (A 8192 u16 + B 4096 u16)

  int bid = blockIdx.x;
  int t = threadIdx.x;
  int wid = t >> 6, lane = t & 63;

  // img -> XCD pinned (8 imgs, 8 XCDs); heavy classes first within each img
  int img = bid & 7;
  int kk = bid >> 3;                       // 0..133
  int mt, oh, Wp, CNT, NTAP, PB, PO, STLIM;
  u32 adj1 = 0, adj2 = 0, adj3 = 0;        // (du*66+dv)*32 u16 per tap (tap0 always 0)
  if (kk < 34)       { int k2 = kk;       mt = k2 >> 1; oh = k2 & 1; Wp = 66; CNT = 4290; NTAP = 4; PB = 0; PO = 0;     STLIM = 4296;
                       adj1 = 2112u; adj2 = 32u; adj3 = 2144u; }
  else if (kk < 68)  { int k2 = kk - 34;  mt = k2 >> 1; oh = k2 & 1; Wp = 64; CNT = 4160; NTAP = 2; PB = 4; PO = 4296;  STLIM = 4160;
                       adj1 = 2112u; }
  else if (kk < 102) { int k2 = kk - 68;  mt = k2 >> 1; oh = k2 & 1; Wp = 66; CNT = 4224; NTAP = 2; PB = 6; PO = 8456;  STLIM = 4224;
                       adj1 = 32u; }
  else               { int k2 = kk - 102; mt = k2 >> 1; oh = k2 & 1; Wp = 64; CNT = 4096; NTAP = 1; PB = 8; PO = 12680; STLIM = 4096; }

  int m0 = mt * 256;
  int o0 = oh * 128;
  int NK = NTAP * 16;                       // K-tiles of 32 ch
  const u16* hb = Hy + (size_t)PB * 131072;

  int wm = wid >> 1, wn = wid & 1;          // 2M x 2N waves: wave = 128m x 64o
  int la = lane & 15, grp = lane >> 4;

  // staging source addrs (pre-swizzled, per issue)
  int tp = t >> 3, ts = t & 7;
  u32 gA[4], gBv[2];
  {
    u32 ib = (u32)img * 2230272u;           // img plane-base (u16)
#pragma unroll
    for (int j = 0; j < 4; ++j) {
      int p = j * 32 + tp;
      int e = ts ^ (p & 7);
      int ii = (e >> 2) * 128 + p;          // logical m-index 0..255
      int kc = e & 3;
      int m = m0 + ii;
      if (m > CNT - 1) m = CNT - 1;         // clamp (garbage compute, store-guarded)
      u32 a = (u32)m / (u32)Wp;
      u32 b = (u32)m - a * (u32)Wp;
      gA[j] = ib + ((a + 1) * 66 + (b + 1)) * 32 + kc * 8;
    }
#pragma unroll
    for (int j = 0; j < 2; ++j) {
      int p = j * 32 + tp;
      int e = ts ^ (p & 7);
      int ol = (e >> 2) * 64 + p;           // logical o-index 0..127
      int kc = e & 3;
      gBv[j] = (u32)((o0 + ol) * 32 + kc * 8);
    }
  }
  int ws = wid * 512;                       // per-wave staging slice (1 KiB)

  f32x4 acc[8][4];
#pragma unroll
  for (int i = 0; i < 8; ++i)
#pragma unroll
    for (int j = 0; j < 4; ++j) acc[i][j] = (f32x4){0.f, 0.f, 0.f, 0.f};

  // ---- prologue: tile0 -> buf0, tile1 -> buf1 (6 ops each); WAITV6 retires tile0
  stB1(hb, su + 8192 + ws, 0, NK, gBv[0]);
  stB1(hb, su + 10240 + ws, 0, NK, gBv[1]);
  stA1(xp, su + 0 + ws, 0, NK, gA[0], adj1, adj2, adj3);
  stA1(xp, su + 2048 + ws, 0, NK, gA[1], adj1, adj2, adj3);
  stA1(xp, su + 4096 + ws, 0, NK, gA[2], adj1, adj2, adj3);
  stA1(xp, su + 6144 + ws, 0, NK, gA[3], adj1, adj2, adj3);
  stB1(hb, su + 12288 + 8192 + ws, 1, NK, gBv[0]);
  stB1(hb, su + 12288 + 10240 + ws, 1, NK, gBv[1]);
  stA1(xp, su + 12288 + 0 + ws, 1, NK, gA[0], adj1, adj2, adj3);
  stA1(xp, su + 12288 + 2048 + ws, 1, NK, gA[1], adj1, adj2, adj3);
  stA1(xp, su + 12288 + 4096 + ws, 1, NK, gA[2], adj1, adj2, adj3);
  stA1(xp, su + 12288 + 6144 + ws, 1, NK, gA[3], adj1, adj2, adj3);
  WAITV6();
  BARR();

  int cur = 0;
#pragma unroll 1
  for (int tt = 0; tt < NK; ++tt) {
    const u16* sb = su + cur * 12288;
    int st2 = cur + 2; if (st2 >= 3) st2 -= 3;
    u16* sd = su + st2 * 12288 + ws;

    // reads: 12 ds_read_b128 per wave (compiler interleaves lgkm with MFMA below)
    bf16x8 af[8], bf[4];
    rdA4(sb, 0, la, grp, wm, af + 0);
    rdB2(sb, 0, la, grp, wn, bf + 0);
    rdB2(sb, 2, la, grp, wn, bf + 2);
    rdA4(sb, 4, la, grp, wm, af + 4);

    // stage tile tt+2 -> buf[(tt+2)%3] (6 DMA ops/wave)
    stA1(xp, sd + 0, tt + 2, NK, gA[0], adj1, adj2, adj3);
    stA1(xp, sd + 2048, tt + 2, NK, gA[1], adj1, adj2, adj3);
    stA1(xp, sd + 4096, tt + 2, NK, gA[2], adj1, adj2, adj3);
    stA1(xp, sd + 6144, tt + 2, NK, gA[3], adj1, adj2, adj3);
    stB1(hb, sd + 8192, tt + 2, NK, gBv[0]);
    stB1(hb, sd + 10240, tt + 2, NK, gBv[1]);

    // 32 MFMA cluster
#pragma unroll
    for (int ti = 0; ti < 8; ++ti)
#pragma unroll
      for (int nj = 0; nj < 4; ++nj)
        acc[ti][nj] = __builtin_amdgcn_mfma_f32_16x16x32_bf16(
            af[ti], bf[nj], acc[ti][nj], 0, 0, 0);

    if (tt + 2 < NK) { WAITV6(); } else { WAITV0(); }
    BARR();
    cur = cur + 1; if (cur >= 3) cur -= 3;
  }

  // ---- epilogue: two o-half rounds through LDS [64 o][256 m] u16 (32 KiB), XOR chunks
  __syncthreads();
  u16* ybp = yb + 8;
#pragma unroll 1
  for (int r = 0; r < 2; ++r) {
    if (wn == r) {
#pragma unroll
      for (int nj = 0; nj < 4; ++nj) {
        int orl = nj * 16 + la;
        int x7 = orl & 7;
#pragma unroll
        for (int mi = 0; mi < 8; ++mi)
#pragma unroll
          for (int jp = 0; jp < 2; ++jp) {
            int ml = wm * 128 + mi * 16 + grp * 4 + jp * 2;
            u32 pk = (u32)f2bf(acc[mi][nj][jp * 2]) |
                     ((u32)f2bf(acc[mi][nj][jp * 2 + 1]) << 16);
            *(u32*)(su + orl * 256 + (((ml >> 3) ^ x7) * 8) + (ml & 7)) = pk;
          }
      }
    }
    __syncthreads();
    {
      int ol = t >> 2, s2 = t & 3;
      int og = o0 + r * 64 + ol;
      size_t gb = (size_t)(img * 256 + og) * CS + PO + m0;
      int x7 = ol & 7;
#pragma unroll
      for (int i = 0; i < 8; ++i) {
        int cidx = s2 * 8 + i;
        int m = cidx * 8;
        if (m0 + m < STLIM)
          *(bf16x8*)(ybp + gb + m) = *(const bf16x8*)(su + ol * 256 + ((cidx ^ x7) * 8));
      }
    }
    if (r == 0) __syncthreads();
  }
}

// ---------------- pass 2: depthwise FIR on planar y; thread = 4p x 8q z block ----------------
// z[p][q] = (1/16) sum f1[s]f1[t] y[p+s-1][q+t-1], f1={1,3,3,1}.
__global__ void fir2(const u16* __restrict__ yb, float* __restrict__ z) {
  int flat = blockIdx.x * 256 + threadIdx.x;
  int qh = flat & 15, phb = (flat >> 4) & 31, o = (flat >> 9) & 255, n = flat >> 17;
  const u16* cb = yb + 8 + (size_t)(n * 256 + o) * CS;
  int a0 = 2 * phb - 1;
  int b0 = 4 * qh - 1;

  float out[4][8];
#pragma unroll
  for (int i = 0; i < 4; ++i)
#pragma unroll
    for (int j = 0; j < 8; ++j) out[i][j] = 0.f;

  const int PO_[4] = {0, 4296, 8456, 12680};
  const int WP_[4] = {66, 64, 66, 64};
  const int HA_[4] = {65, 65, 64, 64};
  const int WB_[4] = {65, 64, 65, 64};

#pragma unroll
  for (int ph = 0; ph < 4; ++ph) {
    int rp = ph >> 1, rq = ph & 1;
    const u16* pb = cb + PO_[ph];
    float hcol[4][8];
#pragma unroll
    for (int la = 0; la < 4; ++la) {
      if (rp == 0 && la == 0) continue;
      int ag = a0 + la;
      bool rv = (ag >= 0) && (ag < HA_[ph]);
      const u16* rb = pb + (ag * WP_[ph] + b0 - 1);
      u32 ls[4];
      ls[0] = *(const u32*)(rb);
      ls[1] = *(const u32*)(rb + 2);
      ls[2] = *(const u32*)(rb + 4);
      ls[3] = *(const u32*)(rb + 6);
      float v[6];
#pragma unroll
      for (int lb = 0; lb < 6; ++lb) {
        int jj = lb + 1;
        u32 w16 = (jj & 1) ? (ls[jj >> 1] >> 16) : (ls[jj >> 1] & 0xffffu);
        float fv = __uint_as_float(w16 << 16);
        int bg = b0 + lb;
        bool ok = rv && (bg >= 0) && (bg < WB_[ph]);
        v[lb] = ok ? fv : 0.f;
      }
#pragma unroll
      for (int e = 0; e < 4; ++e) {
        if (rq == 0) {
          hcol[la][2 * e]     = 3.f * v[e + 1] + v[e + 2];
          hcol[la][2 * e + 1] = v[e + 1] + 3.f * v[e + 2];
        } else {
          hcol[la][2 * e]     = v[e] + 3.f * v[e + 1];
          hcol[la][2 * e + 1] = 3.f * v[e + 1] + v[e + 2];
        }
      }
    }
#pragma unroll
    for (int jq = 0; jq < 8; ++jq) {
      if (rp == 0) {
        out[0][jq] += 3.f * hcol[1][jq] + hcol[2][jq];
        out[1][jq] += hcol[1][jq] + 3.f * hcol[2][jq];
        out[2][jq] += 3.f * hcol[2][jq] + hcol[3][jq];
        out[3][jq] += hcol[2][jq] + 3.f * hcol[3][jq];
      } else {
        out[0][jq] += hcol[0][jq] + 3.f * hcol[1][jq];
        out[1][jq] += 3.f * hcol[1][jq] + hcol[2][jq];
        out[2][jq] += hcol[1][jq] + 3.f * hcol[2][jq];
        out[3][jq] += 3.f * hcol[2][jq] + hcol[3][jq];
      }
    }
  }

  float* zb = z + ((size_t)(n * 256 + o) * 128 + phb * 4) * 128 + qh * 8;
#pragma unroll
  for (int ip = 0; ip < 4; ++ip) {
    f32x4 v0, v1;
#pragma unroll
    for (int j = 0; j < 4; ++j) { v0[j] = out[ip][j] * 0.0625f; v1[j] = out[ip][j + 4] * 0.0625f; }
    *(f32x4*)(zb + (size_t)ip * 128) = v0;
    *(f32x4*)(zb + (size_t)ip * 128 + 4) = v1;
  }
}

// ================= fallback path (R2, proven): FIR-folded fused conv =================
__global__ void xprep_flat(const float* __restrict__ x, u16* __restrict__ xp) {
  __shared__ float tile[64 * 65];
  int bid = blockIdx.x;
  int cc = bid & 7, h = (bid >> 3) & 63, n = bid >> 9;
  int c0 = cc * 64;
  int t = threadIdx.x;
  const float* xb = x + ((size_t)(n * 512 + c0) * 64 + h) * 64;
  for (int r = 0; r < 16; ++r) {
    int flat = r * 256 + t;
    int ci = flat >> 6, w = flat & 63;
    tile[w * 65 + ci] = xb[(size_t)ci * 4096 + w];
  }
  __syncthreads();
  u16* xpb = xp + ((size_t)(n * 66 + h + 1) * 66 + 1) * 512 + c0;
  for (int r = 0; r < 8; ++r) {
    int flat = r * 256 + t;
    int pr = flat & 31;
    int w = flat >> 5;
    int ci = pr * 2;
    float v0 = tile[w * 65 + ci], v1 = tile[w * 65 + ci + 1];
    unsigned pk = (unsigned)f2bf(v0) | ((unsigned)f2bf(v1) << 16);
    *(unsigned*)(xpb + (size_t)w * 512 + ci) = pk;
  }
  u16* rowbase = xp + ((size_t)(n * 66 + h + 1) * 66) * 512 + c0;
  if (t < 32) *(u32*)(rowbase + 2 * t) = 0u;
  else if (t < 64) *(u32*)(rowbase + (size_t)65 * 512 + 2 * (t - 32)) = 0u;
  if (h == 0) {
    u16* r0 = xp + ((size_t)(n * 66) * 66) * 512 + c0;
    for (int j = t; j < 2112; j += 256) {
      int col = j >> 5, wi = j & 31;
      *(u32*)(r0 + (size_t)col * 512 + 2 * wi) = 0u;
    }
  }
  if (h == 63) {
    u16* r65 = xp + ((size_t)(n * 66 + 65) * 66) * 512 + c0;
    for (int j = t; j < 2112; j += 256) {
      int col = j >> 5, wi = j & 31;
      *(u32*)(r65 + (size_t)col * 512 + 2 * wi) = 0u;
    }
  }
}

__global__ void wprep36(const float* __restrict__ w, u16* __restrict__ Hm) {
  __shared__ float wl[4608];
  __shared__ float red[256];
  int o = blockIdx.x, t = threadIdx.x;
  const float* wo = w + (size_t)o * 4608;
  float s = 0.f;
  for (int j = t; j < 4608; j += 256) { float v = wo[j]; wl[j] = v; s += v * v; }
  red[t] = s;
  __syncthreads();
  for (int st = 128; st; st >>= 1) { if (t < st) red[t] += red[t + st]; __syncthreads(); }
  float demod = rsqrtf(red[0] * (1.0f / 4608.0f) + 1e-6f);
  float scale = demod * 0.014731391274719739f;
  const float F1[4] = {1.f, 3.f, 3.f, 1.f};
  for (int i = t; i < 512; i += 256) {
    float wm[9];
    for (int k = 0; k < 9; ++k) wm[k] = wl[i * 9 + k] * scale;
    for (int rp = 0; rp < 2; ++rp)
      for (int rq = 0; rq < 2; ++rq)
        for (int u = 0; u < 3; ++u)
          for (int v = 0; v < 3; ++v) {
            int s_ = 2 - 2 * u + rp, t_ = 2 - 2 * v + rq;
            float g = 0.f;
            for (int dy = 0; dy < 3; ++dy) {
              int a = dy + 1 - s_;
              if (a < 0 || a > 3) continue;
              for (int dx = 0; dx < 3; ++dx) {
                int b = dx + 1 - t_;
                if (b < 0 || b > 3) continue;
                g += wm[dy * 3 + dx] * (F1[a] * F1[b]);
              }
            }
            g *= 0.0625f;
            Hm[(size_t)((rp * 2 + rq) * 9 + u * 3 + v) * 131072 + (size_t)o * 512 + i] = f2bf(g);
          }
  }
}

__global__ __launch_bounds__(256) void conv_main(const u16* __restrict__ xp,
                                                 const u16* __restrict__ Hm,
                                                 float* __restrict__ z) {
  __shared__ __align__(16) float smemf[8448];
  u16* su = (u16*)smemf;
  int bid = blockIdx.x;
  int sub = bid & 7;
  int rp = sub >> 2;
  int o0 = (sub & 3) * 64;
  int mtile = bid >> 3;
  int n_img = mtile >> 5;
  int hp0 = (mtile & 31) * 2;
  int t = threadIdx.x;
  int wave = t >> 6, lane = t & 63;
  int wm0 = (wave & 1) * 64;
  int wn0 = (wave >> 1) * 32;
  int la = lane & 15;
  int ks = (lane >> 4) * 8;
  int rsel = t >> 2;
  int koff = (t & 3) * 8;
  f32x4 acc[2][4][2];
#pragma unroll
  for (int a = 0; a < 2; ++a)
#pragma unroll
    for (int b = 0; b < 4; ++b)
#pragma unroll
      for (int c = 0; c < 2; ++c)
        acc[a][b][c] = (f32x4){0.f, 0.f, 0.f, 0.f};
#pragma unroll 1
  for (int tap = 0; tap < 9; ++tap) {
    int du = tap / 3, dv = tap - du * 3;
    const u16* gA0 = xp + ((size_t)(n_img * 66 + hp0 + du) * 66 + dv) * 512;
    const u16* gB0 = Hm + (size_t)(rp * 18 + tap) * 131072 + (size_t)(o0 + rsel) * 512 + koff;
    const u16* gAr0 = gA0 + (size_t)rsel * 512 + koff;
    const u16* gAr1 = gA0 + (size_t)(66 + rsel) * 512 + koff;
#pragma unroll 1
    for (int kc = 0; kc < 16; ++kc) {
      int c0 = kc * 32;
      __syncthreads();
      gl_lds16(gAr0 + c0, su + wave * 512);
      gl_lds16(gAr1 + c0, su + 2048 + wave * 512);
      gl_lds16(gB0 + c0,              su + 4096 + wave * 512);
      gl_lds16(gB0 + 9 * 131072 + c0, su + 6144 + wave * 512);
      __syncthreads();
      bf16x8 af[4];
#pragma unroll
      for (int ti = 0; ti < 4; ++ti)
        af[ti] = *(const bf16x8*)(su + (wm0 + ti * 16 + la) * 32 + ks);
      bf16x8 bfr[2][2];
#pragma unroll
      for (int rqq = 0; rqq < 2; ++rqq)
#pragma unroll
        for (int tj = 0; tj < 2; ++tj)
          bfr[rqq][tj] = *(const bf16x8*)(su + 4096 + rqq * 2048 + (wn0 + tj * 16 + la) * 32 + ks);
#pragma unroll
      for (int rqq = 0; rqq < 2; ++rqq)
#pragma unroll
        for (int ti = 0; ti < 4; ++ti)
#pragma unroll
          for (int tj = 0; tj < 2; ++tj)
            acc[rqq][ti][tj] = __builtin_amdgcn_mfma_f32_16x16x32_bf16(
                af[ti], bfr[rqq][tj], acc[rqq][ti][tj], 0, 0, 0);
    }
  }
  __syncthreads();
  float* lws = smemf + wave * 2112;
  int p = 2 * (hp0 + (wave & 1)) + rp;
#pragma unroll
  for (int tj = 0; tj < 2; ++tj) {
#pragma unroll
    for (int rqq = 0; rqq < 2; ++rqq)
#pragma unroll
      for (int ti = 0; ti < 4; ++ti) {
        int wqb = ti * 16 + (lane >> 4) * 4;
        f32x4 v = acc[rqq][ti][tj];
#pragma unroll
        for (int r = 0; r < 4; ++r)
          lws[la * 132 + 2 * (wqb + r) + rqq] = v[r];
      }
    __syncthreads();
    int obase = o0 + wn0 + tj * 16;
#pragma unroll
    for (int c = 0; c < 8; ++c) {
      int idx = c * 64 + lane;
      int ol = idx >> 5, q4 = (idx & 31) * 4;
      f32x4 vv = *(const f32x4*)(lws + ol * 132 + q4);
      *(f32x4*)(z + (((size_t)n_img * 256 + obase + ol) * 128 + p) * 128 + q4) = vv;
    }
    __syncthreads();
  }
}

extern "C" void kernel_launch(void* const* d_in, const int* in_sizes, int n_in,
                              void* d_out, int out_size, void* d_ws, size_t ws_size,
                              hipStream_t stream) {
  const float* x = (const float*)d_in[0];
  const float* w = (const float*)d_in[1];
  float* z = (float*)d_out;
  u16* xp = (u16*)d_ws;

  if (ws_size >= WS_NEED) {
    u16* yb = (u16*)((char*)d_ws + XP_BYTES);
    u16* hy = (u16*)((char*)d_ws + HY_OFF);
    xprep<<<4096, 256, 0, stream>>>(x, xp);       // channel-planed; self-zeroing halos
    wprep9<<<256, 256, 0, stream>>>(w, hy);
    conv_y<<<1072, 256, 0, stream>>>(xp, hy, yb); // 8 img x 134 tiles, XCD-pinned, fat-phase
    fir2<<<4096, 256, 0, stream>>>(yb, z);
  } else {
    u16* Hm = (u16*)((char*)d_ws + XP_BYTES);
    hipMemsetAsync(xp, 0, XP_BYTES, stream);
    xprep_flat<<<4096, 256, 0, stream>>>(x, xp);
    wprep36<<<256, 256, 0, stream>>>(w, Hm);
    conv_main<<<2048, 256, 0, stream>>>(xp, Hm, z);
  }
}